// Round 1
// baseline (653.618 us; speedup 1.0000x reference)
//
#include <hip/hip_runtime.h>

// Problem constants (from reference setup_inputs)
constexpr int BZ = 4;
constexpr int C  = 32;
constexpr int H  = 256;
constexpr int W  = 256;
constexpr int NF = 12;
constexpr int HW   = H * W;              // 65536
constexpr long long CHW = (long long)C * H * W;  // 2097152
constexpr int NSLICE = NF * BZ;          // 48

// mae kernel tiling
constexpr int TPB = 256;
constexpr int F4_PER_THREAD = 4;                         // 4 float4 = 16 floats/thread
constexpr int F4_PER_BLOCK  = TPB * F4_PER_THREAD;       // 1024 float4 = 4096 floats
constexpr int BLOCKS_PER_SLICE = (int)(CHW / 4 / F4_PER_BLOCK); // 512

// ---------------------------------------------------------------------------
// Kernel 1: per-slice sum of |x*sal - xf*sal|, hierarchical reduce -> double
// slice s = f*BZ + b  (matches jnp.split(x_focal, NF, axis=0) -> concat axis=1)
// ---------------------------------------------------------------------------
__global__ __launch_bounds__(TPB) void mae_kernel(
    const float* __restrict__ x,
    const float* __restrict__ xf,
    const float* __restrict__ sal,
    double* __restrict__ mae_sum)
{
    const int slice = blockIdx.x / BLOCKS_PER_SLICE;   // 0..47
    const int boff  = blockIdx.x % BLOCKS_PER_SLICE;
    const int b     = slice & (BZ - 1);                // slice % 4

    const float4* __restrict__ xs  = (const float4*)(x   + (long long)b * CHW);
    const float4* __restrict__ xfs = (const float4*)(xf  + (long long)slice * CHW);
    const float4* __restrict__ ss  = (const float4*)(sal + (long long)b * HW);

    float acc = 0.0f;
    const int base = boff * F4_PER_BLOCK + threadIdx.x;  // float4 index within slice
#pragma unroll
    for (int k = 0; k < F4_PER_THREAD; ++k) {
        const int i4 = base + k * TPB;
        const float4 xv = xs[i4];
        const float4 fv = xfs[i4];
        const float4 sv = ss[i4 & (HW / 4 - 1)];         // spatial index (C broadcasts)
        acc += fabsf(xv.x * sv.x - fv.x * sv.x);
        acc += fabsf(xv.y * sv.y - fv.y * sv.y);
        acc += fabsf(xv.z * sv.z - fv.z * sv.z);
        acc += fabsf(xv.w * sv.w - fv.w * sv.w);
    }

    // wave-64 shuffle reduce
#pragma unroll
    for (int off = 32; off > 0; off >>= 1)
        acc += __shfl_down(acc, off, 64);

    __shared__ float wsum[TPB / 64];
    const int wid  = threadIdx.x >> 6;
    const int lane = threadIdx.x & 63;
    if (lane == 0) wsum[wid] = acc;
    __syncthreads();
    if (threadIdx.x == 0) {
        float s = 0.0f;
#pragma unroll
        for (int w = 0; w < TPB / 64; ++w) s += wsum[w];
        atomicAdd(&mae_sum[slice], (double)s);
    }
}

// ---------------------------------------------------------------------------
// Kernel 2: per-batch pair selection. Replicates reference semantics:
// row-major first-max over pairs i<j, strict maxv > 0 else (0,0).
// ---------------------------------------------------------------------------
__global__ void select_kernel(const double* __restrict__ mae_sum,
                              int* __restrict__ sel)
{
    if (blockIdx.x == 0 && threadIdx.x == 0) {
        for (int b = 0; b < BZ; ++b) {
            double mae[NF];
            for (int f = 0; f < NF; ++f)
                mae[f] = mae_sum[f * BZ + b] / (double)CHW;
            double best = 0.0;   // strict '>' vs 0 replicates 'maxv > 0' gate
            int bi = 0, bj = 0;
            for (int i = 0; i < NF; ++i) {
                for (int j = i + 1; j < NF; ++j) {
                    const double d = mae[i] - mae[j];
                    const double v = 0.5 * d * d;
                    if (v > best) { best = v; bi = i; bj = j; }
                }
            }
            sel[b]      = bi;
            sel[BZ + b] = bj;
        }
    }
}

// ---------------------------------------------------------------------------
// Kernel 3: gather selected slices: out[b] = xf[i[b]*BZ+b], out[BZ+b] = xf[j[b]*BZ+b]
// ---------------------------------------------------------------------------
__global__ __launch_bounds__(TPB) void gather_kernel(
    const float* __restrict__ xf,
    const int* __restrict__ sel,
    float* __restrict__ out)
{
    const long long idx = (long long)blockIdx.x * TPB + threadIdx.x; // float4 idx
    const int  o      = (int)(idx >> 19);          // / (CHW/4 = 524288)
    const long long w = idx & ((CHW / 4) - 1);
    const int  b      = o & (BZ - 1);
    const int  half   = o >> 2;                    // 0 -> i, 1 -> j
    const int  f      = sel[half * BZ + b];
    const long long src = (long long)(f * BZ + b) * (CHW / 4) + w;
    ((float4*)out)[idx] = ((const float4*)xf)[src];
}

// ---------------------------------------------------------------------------
extern "C" void kernel_launch(void* const* d_in, const int* in_sizes, int n_in,
                              void* d_out, int out_size, void* d_ws, size_t ws_size,
                              hipStream_t stream)
{
    const float* x   = (const float*)d_in[0];
    const float* xf  = (const float*)d_in[1];
    const float* sal = (const float*)d_in[2];
    float* out = (float*)d_out;

    double* mae_sum = (double*)d_ws;                  // 48 doubles = 384 B
    int*    sel     = (int*)((char*)d_ws + NSLICE * sizeof(double)); // 8 ints

    // ws is poisoned 0xAA before every timed launch -> must zero accumulators
    hipMemsetAsync(d_ws, 0, NSLICE * sizeof(double), stream);

    mae_kernel<<<NSLICE * BLOCKS_PER_SLICE, TPB, 0, stream>>>(x, xf, sal, mae_sum);
    select_kernel<<<1, 64, 0, stream>>>(mae_sum, sel);

    const long long out_f4 = (long long)2 * BZ * CHW / 4;  // 4,194,304
    gather_kernel<<<(int)(out_f4 / TPB), TPB, 0, stream>>>(xf, sel, out);
}